// Round 4
// baseline (179.724 us; speedup 1.0000x reference)
//
#include <hip/hip_runtime.h>

#define TSTEPS 32
#define HID 1024
#define NCLS 10
#define BATCH 8
#define GGRP 32            // groups = H / TSTEPS
#define MROWS 8192         // BATCH * 1024 rows of the big GEMM
#define GK 2048            // K dim (W)
#define GN 1024            // N dim (HIDDEN)

typedef __attribute__((ext_vector_type(8))) short bf16x8;
typedef __attribute__((ext_vector_type(16))) float f32x16;

__device__ __forceinline__ unsigned short bf16_rne(float v) {
    unsigned u = __builtin_bit_cast(unsigned, v);
    return (unsigned short)((u + 0x7FFFu + ((u >> 16) & 1u)) >> 16);
}
__device__ __forceinline__ float bf16_f(unsigned short h) {
    unsigned u = (unsigned)h << 16;
    return __builtin_bit_cast(float, u);
}
__device__ __forceinline__ void gload16(const unsigned short* g, unsigned short* l) {
    __builtin_amdgcn_global_load_lds(
        (const __attribute__((address_space(1))) void*)g,
        (__attribute__((address_space(3))) void*)l, 16, 0, 0);
}

// Packed tile format for 32x32x16 MFMA fragments. Tile = 128 rows x 32 k of
// one matrix, 512 chunks of 8 bf16 (16B). chunk c: u = c>>6 (unit), w = c&63;
// unit u = rowband(u>>1, 32 rows) x khalf(u&1, 16 k); within unit:
// row = (w&31), k-octet = (w>>5). This makes each MFMA fragment read 64
// consecutive chunks: lane l reads chunk (l&31) + 32*(l>>5) -> contiguous 1KB,
// conflict-free, and global_load_lds staging stays linear.

// ---------------- 1x1 conv -> packed bf16 hi/lo A tiles ----------------
__global__ __launch_bounds__(256) void conv_pack_kernel(
    const float4* __restrict__ x, const float* __restrict__ cw,
    const float* __restrict__ cb,
    unsigned short* __restrict__ Ahi, unsigned short* __restrict__ Alo)
{
    const int rb = blockIdx.x >> 6;     // 0..63 row-block
    const int kb = blockIdx.x & 63;     // 0..63 k-block
    const float c0 = cw[0], c1 = cw[1], c2 = cw[2], c3 = cw[3], cbv = cb[0];
    const int tid = threadIdx.x;
#pragma unroll
    for (int cc = 0; cc < 2; ++cc) {
        int c = tid + cc * 256;         // chunk 0..511
        int u = c >> 6, w = c & 63;
        int row = (u >> 1) * 32 + (w & 31);
        int k0  = (u & 1) * 16 + (w >> 5) * 8;
        const float4* px = x + ((size_t)(rb * 128 + row) * 2048 + kb * 32 + k0);
        bf16x8 h8, l8;
#pragma unroll
        for (int e = 0; e < 8; ++e) {
            float4 a = px[e];
            float v = a.x * c0 + a.y * c1 + a.z * c2 + a.w * c3 + cbv;
            unsigned short h = bf16_rne(v);
            h8[e] = (short)h;
            l8[e] = (short)bf16_rne(v - bf16_f(h));
        }
        size_t off = ((size_t)blockIdx.x * 512 + c) * 8;
        *(bf16x8*)(Ahi + off) = h8;
        *(bf16x8*)(Alo + off) = l8;
    }
}

// ---------------- w1 -> packed bf16 hi/lo B tiles ----------------
__global__ __launch_bounds__(256) void wpack_kernel(
    const float* __restrict__ wsrc, unsigned short* __restrict__ Bhi,
    unsigned short* __restrict__ Blo)
{
    const int kb = blockIdx.x & 63;     // blockIdx.x = cbk*64 + kb
    const int cbk = blockIdx.x >> 6;    // 0..7 col-block
    const int tid = threadIdx.x;
#pragma unroll
    for (int cc = 0; cc < 2; ++cc) {
        int c = tid + cc * 256;
        int u = c >> 6, w = c & 63;
        int row = (u >> 1) * 32 + (w & 31);
        int k0  = (u & 1) * 16 + (w >> 5) * 8;
        const float* pw = wsrc + ((size_t)(cbk * 128 + row) * 2048 + kb * 32 + k0);
        bf16x8 h8, l8;
#pragma unroll
        for (int e = 0; e < 8; ++e) {
            float v = pw[e];
            unsigned short h = bf16_rne(v);
            h8[e] = (short)h;
            l8[e] = (short)bf16_rne(v - bf16_f(h));
        }
        size_t off = ((size_t)blockIdx.x * 512 + c) * 8;
        *(bf16x8*)(Bhi + off) = h8;
        *(bf16x8*)(Blo + off) = l8;
    }
}

// ---------------- MFMA GEMM (3-term bf16 split, 32x32x16) + fused scan ----------------
// 128x128 tile, BK=32, 4 waves (2x2 of 64x64 quadrants), double-buffered LDS
// via global_load_lds width-16; STAGE(k+1) issued before MFMA(k), single
// barrier per K-step.
__global__ __launch_bounds__(256) void gemm_scan_kernel(
    const unsigned short* __restrict__ Ahi, const unsigned short* __restrict__ Alo,
    const unsigned short* __restrict__ Bhi, const unsigned short* __restrict__ Blo,
    const float* __restrict__ bias,
    const float* __restrict__ beta1, const float* __restrict__ thr1,
    float* __restrict__ S)
{
    // per buffer (shorts): Ahi[0..4095] Alo[4096..] Bhi[8192..] Blo[12288..]
    __shared__ __align__(16) unsigned short smem[2][16384];   // 64 KB

    const int tid = threadIdx.x;
    const int lane = tid & 63, wv = tid >> 6;
    const int wr = wv >> 1, wc = wv & 1;          // wave quadrant (2x2 of 64x64)
    const int rb = blockIdx.y;                    // 0..63
    const int col0 = blockIdx.x * 128;

    const unsigned short* gAh = Ahi + (size_t)rb * (64 * 4096);
    const unsigned short* gAl = Alo + (size_t)rb * (64 * 4096);
    const unsigned short* gBh = Bhi + (size_t)blockIdx.x * (64 * 4096);
    const unsigned short* gBl = Blo + (size_t)blockIdx.x * (64 * 4096);

    f32x16 acc[2][2];
#pragma unroll
    for (int i = 0; i < 2; ++i)
#pragma unroll
        for (int j = 0; j < 2; ++j) acc[i][j] = (f32x16)0.f;

#define STAGE(buf, kb_)                                                          \
    {                                                                            \
        const size_t tb = (size_t)(kb_) * 4096;                                  \
        unsigned short* dst = &smem[buf][0];                                     \
        _Pragma("unroll")                                                        \
        for (int ii = 0; ii < 2; ++ii) {                                         \
            size_t so = tb + (size_t)(wv * 128 + ii * 64 + lane) * 8;            \
            int dl = (wv * 128 + ii * 64) * 8;                                   \
            gload16(gAh + so, dst + 0 + dl);                                     \
            gload16(gAl + so, dst + 4096 + dl);                                  \
            gload16(gBh + so, dst + 8192 + dl);                                  \
            gload16(gBl + so, dst + 12288 + dl);                                 \
        }                                                                        \
    }

    STAGE(0, 0);
    __syncthreads();

    // fragment chunk offset within a unit (shorts)
    const int fo = ((lane & 31) + 32 * (lane >> 5)) * 8;

    int cur = 0;
    for (int kb = 0; kb < 64; ++kb) {
        if (kb < 63) STAGE(cur ^ 1, kb + 1);

        const unsigned short* bufp = &smem[cur][0];
        bf16x8 ah[2][2], al[2][2], bh[2][2], bl[2][2];
#pragma unroll
        for (int i = 0; i < 2; ++i)
#pragma unroll
            for (int kh = 0; kh < 2; ++kh) {
                int ua = (((wr * 2 + i) * 2 + kh) << 9) + fo;   // unit*512 chunks
                int ub = (((wc * 2 + i) * 2 + kh) << 9) + fo;
                ah[i][kh] = *(const bf16x8*)(bufp + 0 + ua);
                al[i][kh] = *(const bf16x8*)(bufp + 4096 + ua);
                bh[i][kh] = *(const bf16x8*)(bufp + 8192 + ub);
                bl[i][kh] = *(const bf16x8*)(bufp + 12288 + ub);
            }
#pragma unroll
        for (int kh = 0; kh < 2; ++kh) {
#pragma unroll
            for (int i = 0; i < 2; ++i)
#pragma unroll
                for (int j = 0; j < 2; ++j)
                    acc[i][j] = __builtin_amdgcn_mfma_f32_32x32x16_bf16(ah[i][kh], bh[j][kh], acc[i][j], 0, 0, 0);
#pragma unroll
            for (int i = 0; i < 2; ++i)
#pragma unroll
                for (int j = 0; j < 2; ++j)
                    acc[i][j] = __builtin_amdgcn_mfma_f32_32x32x16_bf16(ah[i][kh], bl[j][kh], acc[i][j], 0, 0, 0);
#pragma unroll
            for (int i = 0; i < 2; ++i)
#pragma unroll
                for (int j = 0; j < 2; ++j)
                    acc[i][j] = __builtin_amdgcn_mfma_f32_32x32x16_bf16(al[i][kh], bh[j][kh], acc[i][j], 0, 0, 0);
        }
        __syncthreads();   // drains vmcnt(0): next buffer staged; all done reading cur
        cur ^= 1;
    }

    // ---- fused leaky scan over t (reuse LDS as [64][132] f32 buffer) ----
    float* sb = (float*)&smem[0][0];
    const float bclamp = fminf(fmaxf(beta1[0], 0.f), 1.f);
    const float th = thr1[0];
    const int sbg = tid >> 7;          // 0..1 ((b,g) group within band)
    const int scol = tid & 127;        // 0..127
    const float bv = bias[col0 + scol];

#pragma unroll
    for (int band = 0; band < 2; ++band) {
        if (wr == band) {
#pragma unroll
            for (int i = 0; i < 2; ++i)
#pragma unroll
                for (int j = 0; j < 2; ++j)
#pragma unroll
                    for (int r = 0; r < 16; ++r) {
                        int lr = i * 32 + (r & 3) + 8 * (r >> 2) + 4 * (lane >> 5);
                        int lc = wc * 64 + j * 32 + (lane & 31);
                        sb[lr * 132 + lc] = acc[i][j][r];
                    }
        }
        __syncthreads();
        float mem = 0.f, cnt = 0.f;
#pragma unroll
        for (int t = 0; t < TSTEPS; ++t) {
            float u = sb[(sbg * 32 + t) * 132 + scol] + bv;
            mem = bclamp * mem + u;
            float spk = mem > th ? 1.f : 0.f;
            mem -= spk * th;
            cnt += spk;
        }
        int bgg = ((rb * 128) >> 5) + band * 2 + sbg;
        S[(size_t)bgg * GN + col0 + scol] = cnt;
        __syncthreads();
    }
}

// ---------------- FC2 ----------------
__global__ __launch_bounds__(256) void fc2_kernel(
    const float* __restrict__ s, const float* __restrict__ w2,
    const float* __restrict__ b2, float* __restrict__ h2)
{
    int bg  = blockIdx.x;     // 0..255
    int tid = threadIdx.x;
    const float* sp = s + (size_t)bg * HID;
    float part[NCLS];
#pragma unroll
    for (int c = 0; c < NCLS; ++c) part[c] = 0.f;
    for (int d = tid; d < HID; d += 256) {
        float sv = sp[d];
#pragma unroll
        for (int c = 0; c < NCLS; ++c) part[c] += sv * w2[c * HID + d];
    }
#pragma unroll
    for (int c = 0; c < NCLS; ++c)
        for (int off = 32; off > 0; off >>= 1)
            part[c] += __shfl_down(part[c], off, 64);
    __shared__ float red[NCLS][4];
    int wave = tid >> 6, lanei = tid & 63;
    if (lanei == 0)
#pragma unroll
        for (int c = 0; c < NCLS; ++c) red[c][wave] = part[c];
    __syncthreads();
    if (tid < NCLS) {
        float v = red[tid][0] + red[tid][1] + red[tid][2] + red[tid][3] + b2[tid];
        h2[bg * NCLS + tid] = v;
    }
}

// ---------------- scan over G + softmax ----------------
__global__ __launch_bounds__(128) void scan2_kernel(
    const float* __restrict__ h2, const float* __restrict__ beta2,
    const float* __restrict__ thr2, float* __restrict__ out)
{
    __shared__ float logits[BATCH][NCLS];
    int t = threadIdx.x;
    if (t < BATCH * NCLS) {
        int b = t / NCLS, c = t % NCLS;
        float bb = fminf(fmaxf(beta2[0], 0.f), 1.f);
        float th = thr2[0];
        float mem = 0.f, lg = 0.f;
        for (int g = 0; g < GGRP; ++g) {
            float u = h2[(b * GGRP + g) * NCLS + c];
            mem = bb * mem + u;
            float spk = mem > th ? 1.f : 0.f;
            mem -= spk * th;
            lg += spk;
        }
        logits[b][c] = lg;
    }
    __syncthreads();
    if (t < BATCH) {
        float mx = -1e30f;
        for (int c = 0; c < NCLS; ++c) mx = fmaxf(mx, logits[t][c]);
        float e[NCLS];
        float sum = 0.f;
        for (int c = 0; c < NCLS; ++c) { e[c] = expf(logits[t][c] - mx); sum += e[c]; }
        for (int c = 0; c < NCLS; ++c) out[t * NCLS + c] = e[c] / sum;
    }
}

extern "C" void kernel_launch(void* const* d_in, const int* in_sizes, int n_in,
                              void* d_out, int out_size, void* d_ws, size_t ws_size,
                              hipStream_t stream)
{
    const float* x     = (const float*)d_in[0];
    const float* cw    = (const float*)d_in[1];
    const float* cb    = (const float*)d_in[2];
    const float* w1    = (const float*)d_in[3];
    const float* b1    = (const float*)d_in[4];
    const float* beta1 = (const float*)d_in[5];
    const float* thr1  = (const float*)d_in[6];
    const float* w2    = (const float*)d_in[7];
    const float* b2    = (const float*)d_in[8];
    const float* beta2 = (const float*)d_in[9];
    const float* thr2  = (const float*)d_in[10];
    float* out = (float*)d_out;

    // ws: Ahi 32MB | Alo 32MB | Bhi 4MB | Blo 4MB | s 1MB | h2 10KB (~73MB)
    unsigned short* ahi = (unsigned short*)d_ws;
    unsigned short* alo = ahi + (size_t)MROWS * GK;
    unsigned short* bhi = alo + (size_t)MROWS * GK;
    unsigned short* blo = bhi + (size_t)GN * GK;
    float* s  = (float*)(blo + (size_t)GN * GK);
    float* h2 = s + (size_t)BATCH * GGRP * HID;

    conv_pack_kernel<<<4096, 256, 0, stream>>>((const float4*)x, cw, cb, ahi, alo);
    wpack_kernel    <<<512, 256, 0, stream>>>(w1, bhi, blo);
    gemm_scan_kernel<<<dim3(8, 64), 256, 0, stream>>>(ahi, alo, bhi, blo, b1, beta1, thr1, s);
    fc2_kernel      <<<256, 256, 0, stream>>>(s, w2, b2, h2);
    scan2_kernel    <<<1, 128, 0, stream>>>(h2, beta2, thr2, out);
}

// Round 5
// 177.461 us; speedup vs baseline: 1.0128x; 1.0128x over previous
//
#include <hip/hip_runtime.h>

#define TSTEPS 32
#define HID 1024
#define NCLS 10
#define BATCH 8
#define GGRP 32            // groups = H / TSTEPS
#define MROWS 8192         // BATCH * 1024 rows of the big GEMM
#define GK 2048            // K dim (W)
#define GN 1024            // N dim (HIDDEN)

typedef __attribute__((ext_vector_type(8))) short bf16x8;
typedef __attribute__((ext_vector_type(16))) float f32x16;

__device__ __forceinline__ unsigned short bf16_rne(float v) {
    unsigned u = __builtin_bit_cast(unsigned, v);
    return (unsigned short)((u + 0x7FFFu + ((u >> 16) & 1u)) >> 16);
}
__device__ __forceinline__ float bf16_f(unsigned short h) {
    unsigned u = (unsigned)h << 16;
    return __builtin_bit_cast(float, u);
}
__device__ __forceinline__ void gload16(const unsigned short* g, unsigned short* l) {
    __builtin_amdgcn_global_load_lds(
        (const __attribute__((address_space(1))) void*)g,
        (__attribute__((address_space(3))) void*)l, 16, 0, 0);
}

// Packed tile format for 32x32x16 MFMA fragments. Tile = 128 rows x 32 k of
// one matrix, 512 chunks of 8 bf16 (16B). chunk c: u = c>>6 (unit), w = c&63;
// unit u = rowband(u>>1, 32 rows) x khalf(u&1, 16 k); within unit:
// row = (w&31), k-octet = (w>>5). Each MFMA fragment read is 64 consecutive
// chunks: lane l reads chunk (l&31) + 32*(l>>5) -> contiguous 1KB,
// conflict-free, and global_load_lds staging stays linear (m104 rule).

// ---------------- 1x1 conv -> packed bf16 hi/lo A tiles ----------------
__global__ __launch_bounds__(256) void conv_pack_kernel(
    const float4* __restrict__ x, const float* __restrict__ cw,
    const float* __restrict__ cb,
    unsigned short* __restrict__ Ahi, unsigned short* __restrict__ Alo)
{
    const int rb = blockIdx.x >> 6;     // 0..63 row-block
    const int kb = blockIdx.x & 63;     // 0..63 k-block
    const float c0 = cw[0], c1 = cw[1], c2 = cw[2], c3 = cw[3], cbv = cb[0];
    const int tid = threadIdx.x;
#pragma unroll
    for (int cc = 0; cc < 2; ++cc) {
        int c = tid + cc * 256;         // chunk 0..511
        int u = c >> 6, w = c & 63;
        int row = (u >> 1) * 32 + (w & 31);
        int k0  = (u & 1) * 16 + (w >> 5) * 8;
        const float4* px = x + ((size_t)(rb * 128 + row) * 2048 + kb * 32 + k0);
        bf16x8 h8, l8;
#pragma unroll
        for (int e = 0; e < 8; ++e) {
            float4 a = px[e];
            float v = a.x * c0 + a.y * c1 + a.z * c2 + a.w * c3 + cbv;
            unsigned short h = bf16_rne(v);
            h8[e] = (short)h;
            l8[e] = (short)bf16_rne(v - bf16_f(h));
        }
        size_t off = ((size_t)blockIdx.x * 512 + c) * 8;
        *(bf16x8*)(Ahi + off) = h8;
        *(bf16x8*)(Alo + off) = l8;
    }
}

// ---------------- w1 -> packed bf16 hi/lo B tiles ----------------
__global__ __launch_bounds__(256) void wpack_kernel(
    const float* __restrict__ wsrc, unsigned short* __restrict__ Bhi,
    unsigned short* __restrict__ Blo)
{
    const int kb = blockIdx.x & 63;     // blockIdx.x = cbk*64 + kb
    const int cbk = blockIdx.x >> 6;    // 0..7 col-block
    const int tid = threadIdx.x;
#pragma unroll
    for (int cc = 0; cc < 2; ++cc) {
        int c = tid + cc * 256;
        int u = c >> 6, w = c & 63;
        int row = (u >> 1) * 32 + (w & 31);
        int k0  = (u & 1) * 16 + (w >> 5) * 8;
        const float* pw = wsrc + ((size_t)(cbk * 128 + row) * 2048 + kb * 32 + k0);
        bf16x8 h8, l8;
#pragma unroll
        for (int e = 0; e < 8; ++e) {
            float v = pw[e];
            unsigned short h = bf16_rne(v);
            h8[e] = (short)h;
            l8[e] = (short)bf16_rne(v - bf16_f(h));
        }
        size_t off = ((size_t)blockIdx.x * 512 + c) * 8;
        *(bf16x8*)(Bhi + off) = h8;
        *(bf16x8*)(Blo + off) = l8;
    }
}

// ---------------- MFMA GEMM (3-term bf16 split, 32x32x16) + fused scan ----------------
// 128x128 tile, BK=32, 4 waves (2x2 of 64x64 quadrants). Counted-vmcnt 2-deep
// pipeline: tiles k and k+1 always in flight; raw s_barrier; NO vmcnt(0)
// drain in the main loop (T4). Two barriers per K-step:
//   barrier1: tile k resident (after per-wave vmcnt(8))
//   barrier2: all waves' frags in regs -> buf[k&1] may be overwritten
__global__ __launch_bounds__(256) void gemm_scan_kernel(
    const unsigned short* __restrict__ Ahi, const unsigned short* __restrict__ Alo,
    const unsigned short* __restrict__ Bhi, const unsigned short* __restrict__ Blo,
    const float* __restrict__ bias,
    const float* __restrict__ beta1, const float* __restrict__ thr1,
    float* __restrict__ S)
{
    // per buffer (shorts): Ahi[0..4095] Alo[4096..] Bhi[8192..] Blo[12288..]
    __shared__ __align__(16) unsigned short smem[2][16384];   // 64 KB

    const int tid = threadIdx.x;
    const int lane = tid & 63, wv = tid >> 6;
    const int wr = wv >> 1, wc = wv & 1;          // wave quadrant (2x2 of 64x64)
    const int rb = blockIdx.y;                    // 0..63
    const int col0 = blockIdx.x * 128;

    const unsigned short* gAh = Ahi + (size_t)rb * (64 * 4096);
    const unsigned short* gAl = Alo + (size_t)rb * (64 * 4096);
    const unsigned short* gBh = Bhi + (size_t)blockIdx.x * (64 * 4096);
    const unsigned short* gBl = Blo + (size_t)blockIdx.x * (64 * 4096);

    f32x16 acc[2][2];
#pragma unroll
    for (int i = 0; i < 2; ++i)
#pragma unroll
        for (int j = 0; j < 2; ++j) acc[i][j] = (f32x16)0.f;

#define STAGE(buf, kb_)                                                          \
    {                                                                            \
        const size_t tb = (size_t)(kb_) * 4096;                                  \
        unsigned short* dst = &smem[buf][0];                                     \
        _Pragma("unroll")                                                        \
        for (int ii = 0; ii < 2; ++ii) {                                         \
            size_t so = tb + (size_t)(wv * 128 + ii * 64 + lane) * 8;            \
            int dl = (wv * 128 + ii * 64) * 8;                                   \
            gload16(gAh + so, dst + 0 + dl);                                     \
            gload16(gAl + so, dst + 4096 + dl);                                  \
            gload16(gBh + so, dst + 8192 + dl);                                  \
            gload16(gBl + so, dst + 12288 + dl);                                 \
        }                                                                        \
    }

    // prologue: 2 tiles in flight (16 loads/thread)
    STAGE(0, 0);
    STAGE(1, 1);

    // fragment chunk offset within a unit (shorts)
    const int fo = ((lane & 31) + 32 * (lane >> 5)) * 8;

    for (int kb = 0; kb < 64; ++kb) {
        // tile kb resident once my 8 oldest loads retire (tile kb+1 may fly on)
        if (kb < 63) asm volatile("s_waitcnt vmcnt(8)" ::: "memory");
        else         asm volatile("s_waitcnt vmcnt(0)" ::: "memory");
        __builtin_amdgcn_s_barrier();

        const unsigned short* bufp = &smem[kb & 1][0];
        bf16x8 ah[2][2], al[2][2], bh[2][2], bl[2][2];
#pragma unroll
        for (int i = 0; i < 2; ++i)
#pragma unroll
            for (int kh = 0; kh < 2; ++kh) {
                int ua = (((wr * 2 + i) * 2 + kh) << 9) + fo;   // unit*512 chunks
                int ub = (((wc * 2 + i) * 2 + kh) << 9) + fo;
                ah[i][kh] = *(const bf16x8*)(bufp + 0 + ua);
                al[i][kh] = *(const bf16x8*)(bufp + 4096 + ua);
                bh[i][kh] = *(const bf16x8*)(bufp + 8192 + ub);
                bl[i][kh] = *(const bf16x8*)(bufp + 12288 + ub);
            }
        // all frags in regs before anyone overwrites buf[kb&1]
        asm volatile("s_waitcnt lgkmcnt(0)" ::: "memory");
        __builtin_amdgcn_sched_barrier(0);
        __builtin_amdgcn_s_barrier();

        if (kb < 62) STAGE(kb & 1, kb + 2);   // loads fly under MFMA + next iter

#pragma unroll
        for (int kh = 0; kh < 2; ++kh) {
#pragma unroll
            for (int i = 0; i < 2; ++i)
#pragma unroll
                for (int j = 0; j < 2; ++j)
                    acc[i][j] = __builtin_amdgcn_mfma_f32_32x32x16_bf16(ah[i][kh], bh[j][kh], acc[i][j], 0, 0, 0);
#pragma unroll
            for (int i = 0; i < 2; ++i)
#pragma unroll
                for (int j = 0; j < 2; ++j)
                    acc[i][j] = __builtin_amdgcn_mfma_f32_32x32x16_bf16(ah[i][kh], bl[j][kh], acc[i][j], 0, 0, 0);
#pragma unroll
            for (int i = 0; i < 2; ++i)
#pragma unroll
                for (int j = 0; j < 2; ++j)
                    acc[i][j] = __builtin_amdgcn_mfma_f32_32x32x16_bf16(al[i][kh], bh[j][kh], acc[i][j], 0, 0, 0);
        }
    }

    // ---- fused leaky scan over t (reuse LDS as [64][132] f32 buffer) ----
    float* sb = (float*)&smem[0][0];
    const float bclamp = fminf(fmaxf(beta1[0], 0.f), 1.f);
    const float th = thr1[0];
    const int sbg = tid >> 7;          // 0..1 ((b,g) group within band)
    const int scol = tid & 127;        // 0..127
    const float bv = bias[col0 + scol];

#pragma unroll
    for (int band = 0; band < 2; ++band) {
        if (wr == band) {
#pragma unroll
            for (int i = 0; i < 2; ++i)
#pragma unroll
                for (int j = 0; j < 2; ++j)
#pragma unroll
                    for (int r = 0; r < 16; ++r) {
                        int lr = i * 32 + (r & 3) + 8 * (r >> 2) + 4 * (lane >> 5);
                        int lc = wc * 64 + j * 32 + (lane & 31);
                        sb[lr * 132 + lc] = acc[i][j][r];
                    }
        }
        __syncthreads();
        float mem = 0.f, cnt = 0.f;
#pragma unroll
        for (int t = 0; t < TSTEPS; ++t) {
            float u = sb[(sbg * 32 + t) * 132 + scol] + bv;
            mem = bclamp * mem + u;
            float spk = mem > th ? 1.f : 0.f;
            mem -= spk * th;
            cnt += spk;
        }
        int bgg = ((rb * 128) >> 5) + band * 2 + sbg;
        S[(size_t)bgg * GN + col0 + scol] = cnt;
        __syncthreads();
    }
}

// ---------------- FC2 ----------------
__global__ __launch_bounds__(256) void fc2_kernel(
    const float* __restrict__ s, const float* __restrict__ w2,
    const float* __restrict__ b2, float* __restrict__ h2)
{
    int bg  = blockIdx.x;     // 0..255
    int tid = threadIdx.x;
    const float* sp = s + (size_t)bg * HID;
    float part[NCLS];
#pragma unroll
    for (int c = 0; c < NCLS; ++c) part[c] = 0.f;
    for (int d = tid; d < HID; d += 256) {
        float sv = sp[d];
#pragma unroll
        for (int c = 0; c < NCLS; ++c) part[c] += sv * w2[c * HID + d];
    }
#pragma unroll
    for (int c = 0; c < NCLS; ++c)
        for (int off = 32; off > 0; off >>= 1)
            part[c] += __shfl_down(part[c], off, 64);
    __shared__ float red[NCLS][4];
    int wave = tid >> 6, lanei = tid & 63;
    if (lanei == 0)
#pragma unroll
        for (int c = 0; c < NCLS; ++c) red[c][wave] = part[c];
    __syncthreads();
    if (tid < NCLS) {
        float v = red[tid][0] + red[tid][1] + red[tid][2] + red[tid][3] + b2[tid];
        h2[bg * NCLS + tid] = v;
    }
}

// ---------------- scan over G + softmax ----------------
__global__ __launch_bounds__(128) void scan2_kernel(
    const float* __restrict__ h2, const float* __restrict__ beta2,
    const float* __restrict__ thr2, float* __restrict__ out)
{
    __shared__ float logits[BATCH][NCLS];
    int t = threadIdx.x;
    if (t < BATCH * NCLS) {
        int b = t / NCLS, c = t % NCLS;
        float bb = fminf(fmaxf(beta2[0], 0.f), 1.f);
        float th = thr2[0];
        float mem = 0.f, lg = 0.f;
        for (int g = 0; g < GGRP; ++g) {
            float u = h2[(b * GGRP + g) * NCLS + c];
            mem = bb * mem + u;
            float spk = mem > th ? 1.f : 0.f;
            mem -= spk * th;
            lg += spk;
        }
        logits[b][c] = lg;
    }
    __syncthreads();
    if (t < BATCH) {
        float mx = -1e30f;
        for (int c = 0; c < NCLS; ++c) mx = fmaxf(mx, logits[t][c]);
        float e[NCLS];
        float sum = 0.f;
        for (int c = 0; c < NCLS; ++c) { e[c] = expf(logits[t][c] - mx); sum += e[c]; }
        for (int c = 0; c < NCLS; ++c) out[t * NCLS + c] = e[c] / sum;
    }
}

extern "C" void kernel_launch(void* const* d_in, const int* in_sizes, int n_in,
                              void* d_out, int out_size, void* d_ws, size_t ws_size,
                              hipStream_t stream)
{
    const float* x     = (const float*)d_in[0];
    const float* cw    = (const float*)d_in[1];
    const float* cb    = (const float*)d_in[2];
    const float* w1    = (const float*)d_in[3];
    const float* b1    = (const float*)d_in[4];
    const float* beta1 = (const float*)d_in[5];
    const float* thr1  = (const float*)d_in[6];
    const float* w2    = (const float*)d_in[7];
    const float* b2    = (const float*)d_in[8];
    const float* beta2 = (const float*)d_in[9];
    const float* thr2  = (const float*)d_in[10];
    float* out = (float*)d_out;

    // ws: Ahi 32MB | Alo 32MB | Bhi 4MB | Blo 4MB | s 1MB | h2 10KB (~73MB)
    unsigned short* ahi = (unsigned short*)d_ws;
    unsigned short* alo = ahi + (size_t)MROWS * GK;
    unsigned short* bhi = alo + (size_t)MROWS * GK;
    unsigned short* blo = bhi + (size_t)GN * GK;
    float* s  = (float*)(blo + (size_t)GN * GK);
    float* h2 = s + (size_t)BATCH * GGRP * HID;

    conv_pack_kernel<<<4096, 256, 0, stream>>>((const float4*)x, cw, cb, ahi, alo);
    wpack_kernel    <<<512, 256, 0, stream>>>(w1, bhi, blo);
    gemm_scan_kernel<<<dim3(8, 64), 256, 0, stream>>>(ahi, alo, bhi, blo, b1, beta1, thr1, s);
    fc2_kernel      <<<256, 256, 0, stream>>>(s, w2, b2, h2);
    scan2_kernel    <<<1, 128, 0, stream>>>(h2, beta2, thr2, out);
}

// Round 6
// 171.563 us; speedup vs baseline: 1.0476x; 1.0344x over previous
//
#include <hip/hip_runtime.h>

#define TSTEPS 32
#define HID 1024
#define NCLS 10
#define BATCH 8
#define GGRP 32            // groups = H / TSTEPS
#define MROWS 8192         // BATCH * 1024 rows of the big GEMM
#define GK 2048            // K dim (W)
#define GN 1024            // N dim (HIDDEN)
#define BUFSH 24576        // shorts per LDS buffer (A 8K + B 16K shorts)

typedef __attribute__((ext_vector_type(8))) short bf16x8;
typedef __attribute__((ext_vector_type(16))) float f32x16;

__device__ __forceinline__ unsigned short bf16_rne(float v) {
    unsigned u = __builtin_bit_cast(unsigned, v);
    return (unsigned short)((u + 0x7FFFu + ((u >> 16) & 1u)) >> 16);
}
__device__ __forceinline__ float bf16_f(unsigned short h) {
    unsigned u = (unsigned)h << 16;
    return __builtin_bit_cast(float, u);
}
__device__ __forceinline__ void gload16(const unsigned short* g, unsigned short* l) {
    __builtin_amdgcn_global_load_lds(
        (const __attribute__((address_space(1))) void*)g,
        (__attribute__((address_space(3))) void*)l, 16, 0, 0);
}

// A tile = 128 rows x 32 k, 512 chunks of 8 bf16 (16B): chunk c: u=c>>6 (unit =
// rowband(u>>1, 32 rows) x khalf(u&1, 16 k)), w=c&63: row=(w&31), koct=(w>>5).
// B tile = 256 rows x 32 k, 1024 chunks, same unit scheme (16 units).
// MFMA fragment read = 64 consecutive chunks (lane l -> chunk (l&31)+32*(l>>5))
// -> contiguous 1KB, conflict-free; global_load_lds staging stays linear.

// ---------------- 1x1 conv -> packed bf16 hi/lo A tiles ----------------
__global__ __launch_bounds__(256) void conv_pack_kernel(
    const float4* __restrict__ x, const float* __restrict__ cw,
    const float* __restrict__ cb,
    unsigned short* __restrict__ Ahi, unsigned short* __restrict__ Alo)
{
    const int rb = blockIdx.x >> 6;     // 0..63 row-block
    const int kb = blockIdx.x & 63;     // 0..63 k-block
    const float c0 = cw[0], c1 = cw[1], c2 = cw[2], c3 = cw[3], cbv = cb[0];
    const int tid = threadIdx.x;
#pragma unroll
    for (int cc = 0; cc < 2; ++cc) {
        int c = tid + cc * 256;         // chunk 0..511
        int u = c >> 6, w = c & 63;
        int row = (u >> 1) * 32 + (w & 31);
        int k0  = (u & 1) * 16 + (w >> 5) * 8;
        const float4* px = x + ((size_t)(rb * 128 + row) * 2048 + kb * 32 + k0);
        bf16x8 h8, l8;
#pragma unroll
        for (int e = 0; e < 8; ++e) {
            float4 a = px[e];
            float v = a.x * c0 + a.y * c1 + a.z * c2 + a.w * c3 + cbv;
            unsigned short h = bf16_rne(v);
            h8[e] = (short)h;
            l8[e] = (short)bf16_rne(v - bf16_f(h));
        }
        size_t off = ((size_t)blockIdx.x * 512 + c) * 8;
        *(bf16x8*)(Ahi + off) = h8;
        *(bf16x8*)(Alo + off) = l8;
    }
}

// ---------------- w1 -> packed bf16 hi/lo B tiles (256-col tiles) ----------------
__global__ __launch_bounds__(256) void wpack_kernel(
    const float* __restrict__ wsrc, unsigned short* __restrict__ Bhi,
    unsigned short* __restrict__ Blo)
{
    const int kb  = blockIdx.x & 63;    // blockIdx.x = cbk*64 + kb
    const int cbk = blockIdx.x >> 6;    // 0..3 col-block
    const int tid = threadIdx.x;
#pragma unroll
    for (int cc = 0; cc < 4; ++cc) {
        int c = tid + cc * 256;         // chunk 0..1023
        int u = c >> 6, w = c & 63;
        int col = cbk * 256 + (u >> 1) * 32 + (w & 31);
        int k0  = kb * 32 + (u & 1) * 16 + (w >> 5) * 8;
        const float* pw = wsrc + ((size_t)col * 2048 + k0);
        bf16x8 h8, l8;
#pragma unroll
        for (int e = 0; e < 8; ++e) {
            float v = pw[e];
            unsigned short h = bf16_rne(v);
            h8[e] = (short)h;
            l8[e] = (short)bf16_rne(v - bf16_f(h));
        }
        size_t off = ((size_t)blockIdx.x * 1024 + c) * 8;
        *(bf16x8*)(Bhi + off) = h8;
        *(bf16x8*)(Blo + off) = l8;
    }
}

// ---------------- MFMA GEMM (3-term bf16 split, 32x32x16) + fused scan ----------------
// 128x256 tile, BK=32, 8 waves (2x4 of 64x64 quadrants), 512 threads,
// triple-buffered LDS (144 KB): tiles kb,kb+1 in flight, STAGE(kb+2) after the
// single barrier; counted vmcnt(6), no vmcnt(0) drain in the loop.
// 1-D grid, by = wgid&63, bx = wgid>>6 -> XCD = wgid%8 = by%8: all 4
// col-blocks of an A row-panel co-reside on one XCD (A from L2, not L3).
__global__ __launch_bounds__(512) void gemm_scan_kernel(
    const unsigned short* __restrict__ Ahi, const unsigned short* __restrict__ Alo,
    const unsigned short* __restrict__ Bhi, const unsigned short* __restrict__ Blo,
    const float* __restrict__ bias,
    const float* __restrict__ beta1, const float* __restrict__ thr1,
    float* __restrict__ S)
{
    // per buffer (shorts): Ahi[0,4096) Alo[4096,8192) Bhi[8192,16384) Blo[16384,24576)
    __shared__ __align__(16) unsigned short sm[3 * BUFSH];   // 147,456 B

    const int tid = threadIdx.x;
    const int lane = tid & 63, wv = tid >> 6;
    const int wr = wv >> 2, wc = wv & 3;          // wave quadrant (2x4 of 64x64)
    const int by = blockIdx.x & 63;               // A row-panel
    const int bx = blockIdx.x >> 6;               // B col-panel 0..3

    const unsigned short* gAh = Ahi + (size_t)by * 262144;
    const unsigned short* gAl = Alo + (size_t)by * 262144;
    const unsigned short* gBh = Bhi + (size_t)bx * 524288;
    const unsigned short* gBl = Blo + (size_t)bx * 524288;

    f32x16 acc[2][2];
#pragma unroll
    for (int i = 0; i < 2; ++i)
#pragma unroll
        for (int j = 0; j < 2; ++j) acc[i][j] = (f32x16)0.f;

#define STAGE(buf, kb_)                                                          \
    {                                                                            \
        unsigned short* dst = sm + (buf) * BUFSH;                                \
        const size_t ao = (size_t)(kb_) * 4096 + tid * 8;                        \
        const size_t bo = (size_t)(kb_) * 8192 + tid * 8;                        \
        gload16(gAh + ao, dst + tid * 8);                                        \
        gload16(gAl + ao, dst + 4096 + tid * 8);                                 \
        gload16(gBh + bo, dst + 8192 + tid * 8);                                 \
        gload16(gBh + bo + 4096, dst + 12288 + tid * 8);                         \
        gload16(gBl + bo, dst + 16384 + tid * 8);                                \
        gload16(gBl + bo + 4096, dst + 20480 + tid * 8);                         \
    }

    // prologue: 2 tiles in flight (12 wave-loads)
    STAGE(0, 0);
    STAGE(1, 1);

    // fragment chunk offset within a unit (shorts)
    const int fo = ((lane & 31) + 32 * (lane >> 5)) * 8;

    int cur = 0;
    for (int kb = 0; kb < 64; ++kb) {
        // tile kb resident once this wave's 6 oldest loads retire
        if (kb < 63) asm volatile("s_waitcnt vmcnt(6)" ::: "memory");
        else         asm volatile("s_waitcnt vmcnt(0)" ::: "memory");
        __builtin_amdgcn_s_barrier();   // all waves' tile-kb loads are in LDS

        int nbuf = cur + 2; if (nbuf >= 3) nbuf -= 3;
        if (kb < 62) STAGE(nbuf, kb + 2);   // flies under this + next iteration

        const unsigned short* bufp = sm + cur * BUFSH;
        bf16x8 ah[2][2], al[2][2], bh[2][2], bl[2][2];
#pragma unroll
        for (int i = 0; i < 2; ++i)
#pragma unroll
            for (int kh = 0; kh < 2; ++kh) {
                int ua = (((wr * 2 + i) * 2 + kh) << 9) + fo;
                ah[i][kh] = *(const bf16x8*)(bufp + ua);
                al[i][kh] = *(const bf16x8*)(bufp + 4096 + ua);
            }
#pragma unroll
        for (int j = 0; j < 2; ++j)
#pragma unroll
            for (int kh = 0; kh < 2; ++kh) {
                int ub = (((wc * 2 + j) * 2 + kh) << 9) + fo;
                bh[j][kh] = *(const bf16x8*)(bufp + 8192 + ub);
                bl[j][kh] = *(const bf16x8*)(bufp + 16384 + ub);
            }
#pragma unroll
        for (int kh = 0; kh < 2; ++kh) {
#pragma unroll
            for (int i = 0; i < 2; ++i)
#pragma unroll
                for (int j = 0; j < 2; ++j)
                    acc[i][j] = __builtin_amdgcn_mfma_f32_32x32x16_bf16(ah[i][kh], bh[j][kh], acc[i][j], 0, 0, 0);
#pragma unroll
            for (int i = 0; i < 2; ++i)
#pragma unroll
                for (int j = 0; j < 2; ++j)
                    acc[i][j] = __builtin_amdgcn_mfma_f32_32x32x16_bf16(ah[i][kh], bl[j][kh], acc[i][j], 0, 0, 0);
#pragma unroll
            for (int i = 0; i < 2; ++i)
#pragma unroll
                for (int j = 0; j < 2; ++j)
                    acc[i][j] = __builtin_amdgcn_mfma_f32_32x32x16_bf16(al[i][kh], bh[j][kh], acc[i][j], 0, 0, 0);
        }
        cur = (cur == 2) ? 0 : cur + 1;
    }
    __syncthreads();   // all waves done reading LDS before epilogue overwrites it

    // ---- fused leaky scan over t (reuse LDS as [64][256] f32 buffer, 64 KB) ----
    float* sb = (float*)sm;
    const float bclamp = fminf(fmaxf(beta1[0], 0.f), 1.f);
    const float th = thr1[0];
    const int sbg = tid >> 8;          // 0..1 ((b,g) group within band)
    const int scol = tid & 255;        // 0..255
    const float bv = bias[bx * 256 + scol];

#pragma unroll
    for (int band = 0; band < 2; ++band) {
        if (wr == band) {
#pragma unroll
            for (int i = 0; i < 2; ++i)
#pragma unroll
                for (int j = 0; j < 2; ++j)
#pragma unroll
                    for (int r = 0; r < 16; ++r) {
                        int lr = i * 32 + (r & 3) + 8 * (r >> 2) + 4 * (lane >> 5);
                        int lc = wc * 64 + j * 32 + (lane & 31);
                        sb[lr * 256 + lc] = acc[i][j][r];
                    }
        }
        __syncthreads();
        float mem = 0.f, cnt = 0.f;
#pragma unroll
        for (int t = 0; t < TSTEPS; ++t) {
            float u = sb[(sbg * 32 + t) * 256 + scol] + bv;
            mem = bclamp * mem + u;
            float spk = mem > th ? 1.f : 0.f;
            mem -= spk * th;
            cnt += spk;
        }
        int bgg = by * 4 + band * 2 + sbg;
        S[(size_t)bgg * GN + bx * 256 + scol] = cnt;
        __syncthreads();
    }
}

// ---------------- FC2 ----------------
__global__ __launch_bounds__(256) void fc2_kernel(
    const float* __restrict__ s, const float* __restrict__ w2,
    const float* __restrict__ b2, float* __restrict__ h2)
{
    int bg  = blockIdx.x;     // 0..255
    int tid = threadIdx.x;
    const float* sp = s + (size_t)bg * HID;
    float part[NCLS];
#pragma unroll
    for (int c = 0; c < NCLS; ++c) part[c] = 0.f;
    for (int d = tid; d < HID; d += 256) {
        float sv = sp[d];
#pragma unroll
        for (int c = 0; c < NCLS; ++c) part[c] += sv * w2[c * HID + d];
    }
#pragma unroll
    for (int c = 0; c < NCLS; ++c)
        for (int off = 32; off > 0; off >>= 1)
            part[c] += __shfl_down(part[c], off, 64);
    __shared__ float red[NCLS][4];
    int wave = tid >> 6, lanei = tid & 63;
    if (lanei == 0)
#pragma unroll
        for (int c = 0; c < NCLS; ++c) red[c][wave] = part[c];
    __syncthreads();
    if (tid < NCLS) {
        float v = red[tid][0] + red[tid][1] + red[tid][2] + red[tid][3] + b2[tid];
        h2[bg * NCLS + tid] = v;
    }
}

// ---------------- scan over G + softmax ----------------
__global__ __launch_bounds__(128) void scan2_kernel(
    const float* __restrict__ h2, const float* __restrict__ beta2,
    const float* __restrict__ thr2, float* __restrict__ out)
{
    __shared__ float logits[BATCH][NCLS];
    int t = threadIdx.x;
    if (t < BATCH * NCLS) {
        int b = t / NCLS, c = t % NCLS;
        float bb = fminf(fmaxf(beta2[0], 0.f), 1.f);
        float th = thr2[0];
        float mem = 0.f, lg = 0.f;
        for (int g = 0; g < GGRP; ++g) {
            float u = h2[(b * GGRP + g) * NCLS + c];
            mem = bb * mem + u;
            float spk = mem > th ? 1.f : 0.f;
            mem -= spk * th;
            lg += spk;
        }
        logits[b][c] = lg;
    }
    __syncthreads();
    if (t < BATCH) {
        float mx = -1e30f;
        for (int c = 0; c < NCLS; ++c) mx = fmaxf(mx, logits[t][c]);
        float e[NCLS];
        float sum = 0.f;
        for (int c = 0; c < NCLS; ++c) { e[c] = expf(logits[t][c] - mx); sum += e[c]; }
        for (int c = 0; c < NCLS; ++c) out[t * NCLS + c] = e[c] / sum;
    }
}

extern "C" void kernel_launch(void* const* d_in, const int* in_sizes, int n_in,
                              void* d_out, int out_size, void* d_ws, size_t ws_size,
                              hipStream_t stream)
{
    const float* x     = (const float*)d_in[0];
    const float* cw    = (const float*)d_in[1];
    const float* cb    = (const float*)d_in[2];
    const float* w1    = (const float*)d_in[3];
    const float* b1    = (const float*)d_in[4];
    const float* beta1 = (const float*)d_in[5];
    const float* thr1  = (const float*)d_in[6];
    const float* w2    = (const float*)d_in[7];
    const float* b2    = (const float*)d_in[8];
    const float* beta2 = (const float*)d_in[9];
    const float* thr2  = (const float*)d_in[10];
    float* out = (float*)d_out;

    // ws: Ahi 32MB | Alo 32MB | Bhi 4MB | Blo 4MB | s 1MB | h2 10KB (~73MB)
    unsigned short* ahi = (unsigned short*)d_ws;
    unsigned short* alo = ahi + (size_t)MROWS * GK;
    unsigned short* bhi = alo + (size_t)MROWS * GK;
    unsigned short* blo = bhi + (size_t)GN * GK;
    float* s  = (float*)(blo + (size_t)GN * GK);
    float* h2 = s + (size_t)BATCH * GGRP * HID;

    conv_pack_kernel<<<4096, 256, 0, stream>>>((const float4*)x, cw, cb, ahi, alo);
    wpack_kernel    <<<256, 256, 0, stream>>>(w1, bhi, blo);
    gemm_scan_kernel<<<256, 512, 0, stream>>>(ahi, alo, bhi, blo, b1, beta1, thr1, s);
    fc2_kernel      <<<256, 256, 0, stream>>>(s, w2, b2, h2);
    scan2_kernel    <<<1, 128, 0, stream>>>(h2, beta2, thr2, out);
}

// Round 8
// 154.875 us; speedup vs baseline: 1.1604x; 1.1077x over previous
//
#include <hip/hip_runtime.h>

#define TSTEPS 32
#define HID 1024
#define NCLS 10
#define BATCH 8
#define GGRP 32            // groups = H / TSTEPS
#define MROWS 8192         // BATCH * 1024 rows of the big GEMM
#define GK 2048            // K dim (W)
#define GN 1024            // N dim (HIDDEN)
#define BUFSH 24576        // shorts per LDS buffer (A 8K + B 16K shorts)
#define CLDS 40            // conv LDS row pitch in shorts (80B, 16B aligned)

typedef __attribute__((ext_vector_type(8))) short bf16x8;
typedef __attribute__((ext_vector_type(16))) float f32x16;

__device__ __forceinline__ unsigned short bf16_rne(float v) {
    unsigned u = __builtin_bit_cast(unsigned, v);
    return (unsigned short)((u + 0x7FFFu + ((u >> 16) & 1u)) >> 16);
}
__device__ __forceinline__ float bf16_f(unsigned short h) {
    unsigned u = (unsigned)h << 16;
    return __builtin_bit_cast(float, u);
}
__device__ __forceinline__ void gload16(const unsigned short* g, unsigned short* l) {
    __builtin_amdgcn_global_load_lds(
        (const __attribute__((address_space(1))) void*)g,
        (__attribute__((address_space(3))) void*)l, 16, 0, 0);
}

// A tile = 128 rows x 32 k, 512 chunks of 8 bf16 (16B): chunk c: u=c>>6 (unit =
// rowband(u>>1, 32 rows) x khalf(u&1, 16 k)), w=c&63: row=(w&31), koct=(w>>5).
// B tile = 256 rows x 32 k, 1024 chunks, same unit scheme (16 units).
// MFMA fragment read = 64 consecutive chunks (lane l -> chunk (l&31)+32*(l>>5))
// -> contiguous 1KB, conflict-free; global_load_lds staging stays linear.

// ---------------- 1x1 conv -> packed bf16 hi/lo A tiles (LDS-staged) ----------------
__global__ __launch_bounds__(256) void conv_pack_kernel(
    const float4* __restrict__ x, const float* __restrict__ cw,
    const float* __restrict__ cb,
    unsigned short* __restrict__ Ahi, unsigned short* __restrict__ Alo)
{
    __shared__ __align__(16) unsigned short lh[128 * CLDS];
    __shared__ __align__(16) unsigned short ll[128 * CLDS];
    const int rb = blockIdx.x >> 6;     // 0..63 row-block
    const int kb = blockIdx.x & 63;     // 0..63 k-block
    const float c0 = cw[0], c1 = cw[1], c2 = cw[2], c3 = cw[3], cbv = cb[0];
    const int tid = threadIdx.x;

    // phase 1: coalesced 16B/lane reads, conv, LDS write
#pragma unroll
    for (int p = 0; p < 16; ++p) {
        int i = p * 256 + tid;          // 0..4095 over [128 rows][32 px]
        int row = i >> 5, px = i & 31;
        float4 a = x[(size_t)(rb * 128 + row) * 2048 + kb * 32 + px];
        float v = a.x * c0 + a.y * c1 + a.z * c2 + a.w * c3 + cbv;
        unsigned short h = bf16_rne(v);
        lh[row * CLDS + px] = h;
        ll[row * CLDS + px] = bf16_rne(v - bf16_f(h));
    }
    __syncthreads();

    // phase 2: emit packed chunks; stores are 16B/lane contiguous across waves
#pragma unroll
    for (int cc = 0; cc < 2; ++cc) {
        int c = tid + cc * 256;         // chunk 0..511
        int u = c >> 6, w = c & 63;
        int row = (u >> 1) * 32 + (w & 31);
        int ko  = (u & 1) * 2 + (w >> 5);   // k-octet 0..3
        bf16x8 h8 = *(const bf16x8*)(lh + row * CLDS + ko * 8);
        bf16x8 l8 = *(const bf16x8*)(ll + row * CLDS + ko * 8);
        size_t off = ((size_t)blockIdx.x * 512 + c) * 8;
        *(bf16x8*)(Ahi + off) = h8;
        *(bf16x8*)(Alo + off) = l8;
    }
}

// ---------------- w1 -> packed bf16 hi/lo B tiles (256-col tiles) ----------------
__global__ __launch_bounds__(256) void wpack_kernel(
    const float* __restrict__ wsrc, unsigned short* __restrict__ Bhi,
    unsigned short* __restrict__ Blo)
{
    const int kb  = blockIdx.x & 63;    // blockIdx.x = cbk*64 + kb
    const int cbk = blockIdx.x >> 6;    // 0..3 col-block
    const int tid = threadIdx.x;
#pragma unroll
    for (int cc = 0; cc < 4; ++cc) {
        int c = tid + cc * 256;         // chunk 0..1023
        int u = c >> 6, w = c & 63;
        int col = cbk * 256 + (u >> 1) * 32 + (w & 31);
        int k0  = kb * 32 + (u & 1) * 16 + (w >> 5) * 8;
        const float* pw = wsrc + ((size_t)col * 2048 + k0);
        bf16x8 h8, l8;
#pragma unroll
        for (int e = 0; e < 8; ++e) {
            float v = pw[e];
            unsigned short h = bf16_rne(v);
            h8[e] = (short)h;
            l8[e] = (short)bf16_rne(v - bf16_f(h));
        }
        size_t off = ((size_t)blockIdx.x * 1024 + c) * 8;
        *(bf16x8*)(Bhi + off) = h8;
        *(bf16x8*)(Blo + off) = l8;
    }
}

// ---------------- MFMA GEMM (3-term bf16 split, 32x32x16) + fused scan ----------------
// 128x256 tile, BK=32, 8 waves (2x4 of 64x64), 512 threads, triple-buffered LDS.
// One-step software pipeline (corrected schedule):
//   iteration KB: tile KB-1's frags in regs (set SC) -> MFMA them;
//   read tile KB's frags (set SN) from buf KB%3, reads fly under MFMAs;
//   STAGE tile KB+2 into buf (KB+2)%3 (freed: tile KB-1 fully read by all
//   waves, guaranteed by lgkmcnt(0)+barrier this iteration).
// Wait math: entry outstanding = my 6 loads each of tiles KB, KB+1 ->
//   vmcnt(6) = tile KB resident (vmcnt(0) at KB=63, where only 6 remain).
__global__ __launch_bounds__(512) void gemm_scan_kernel(
    const unsigned short* __restrict__ Ahi, const unsigned short* __restrict__ Alo,
    const unsigned short* __restrict__ Bhi, const unsigned short* __restrict__ Blo,
    const float* __restrict__ bias,
    const float* __restrict__ beta1, const float* __restrict__ thr1,
    float* __restrict__ S)
{
    // per buffer (shorts): Ahi[0,4096) Alo[4096,8192) Bhi[8192,16384) Blo[16384,24576)
    __shared__ __align__(16) unsigned short sm[3 * BUFSH];   // 147,456 B

    const int tid = threadIdx.x;
    const int lane = tid & 63, wv = tid >> 6;
    const int wr = wv >> 2, wc = wv & 3;          // wave quadrant (2x4 of 64x64)
    const int by = blockIdx.x & 63;               // A row-panel (XCD = by%8)
    const int bx = blockIdx.x >> 6;               // B col-panel 0..3

    const unsigned short* gAh = Ahi + (size_t)by * 262144;
    const unsigned short* gAl = Alo + (size_t)by * 262144;
    const unsigned short* gBh = Bhi + (size_t)bx * 524288;
    const unsigned short* gBl = Blo + (size_t)bx * 524288;

    f32x16 acc[2][2];
#pragma unroll
    for (int i = 0; i < 2; ++i)
#pragma unroll
        for (int j = 0; j < 2; ++j) acc[i][j] = (f32x16)0.f;

    // frag sets: [set][0..7]=A (i,kh,hi/lo), [set][8..15]=B (j,kh,hi/lo)
    bf16x8 fr[2][16];

#define STAGE(buf, kb_)                                                          \
    {                                                                            \
        unsigned short* dst = sm + (buf) * BUFSH;                                \
        const size_t ao = (size_t)(kb_) * 4096 + tid * 8;                        \
        const size_t bo = (size_t)(kb_) * 8192 + tid * 8;                        \
        gload16(gAh + ao, dst + tid * 8);                                        \
        gload16(gAl + ao, dst + 4096 + tid * 8);                                 \
        gload16(gBh + bo, dst + 8192 + tid * 8);                                 \
        gload16(gBh + bo + 4096, dst + 12288 + tid * 8);                         \
        gload16(gBl + bo, dst + 16384 + tid * 8);                                \
        gload16(gBl + bo + 4096, dst + 20480 + tid * 8);                         \
    }

#define READF(s, bufp)                                                           \
    {                                                                            \
        const unsigned short* bp_ = (bufp);                                      \
        _Pragma("unroll")                                                        \
        for (int i = 0; i < 2; ++i)                                              \
            _Pragma("unroll")                                                    \
            for (int kh = 0; kh < 2; ++kh) {                                     \
                int ua = (((wr * 2 + i) * 2 + kh) << 9) + fo;                    \
                fr[s][(i * 2 + kh) * 2 + 0] = *(const bf16x8*)(bp_ + ua);        \
                fr[s][(i * 2 + kh) * 2 + 1] = *(const bf16x8*)(bp_ + 4096 + ua); \
            }                                                                    \
        _Pragma("unroll")                                                        \
        for (int j = 0; j < 2; ++j)                                              \
            _Pragma("unroll")                                                    \
            for (int kh = 0; kh < 2; ++kh) {                                     \
                int ub = (((wc * 2 + j) * 2 + kh) << 9) + fo;                    \
                fr[s][8 + (j * 2 + kh) * 2 + 0] = *(const bf16x8*)(bp_ + 8192 + ub);  \
                fr[s][8 + (j * 2 + kh) * 2 + 1] = *(const bf16x8*)(bp_ + 16384 + ub); \
            }                                                                    \
    }

#define MFMAF(s)                                                                 \
    {                                                                            \
        _Pragma("unroll")                                                        \
        for (int kh = 0; kh < 2; ++kh) {                                         \
            _Pragma("unroll")                                                    \
            for (int i = 0; i < 2; ++i)                                          \
                _Pragma("unroll")                                                \
                for (int j = 0; j < 2; ++j)                                      \
                    acc[i][j] = __builtin_amdgcn_mfma_f32_32x32x16_bf16(         \
                        fr[s][(i * 2 + kh) * 2], fr[s][8 + (j * 2 + kh) * 2],    \
                        acc[i][j], 0, 0, 0);                                     \
            _Pragma("unroll")                                                    \
            for (int i = 0; i < 2; ++i)                                          \
                _Pragma("unroll")                                                \
                for (int j = 0; j < 2; ++j)                                      \
                    acc[i][j] = __builtin_amdgcn_mfma_f32_32x32x16_bf16(         \
                        fr[s][(i * 2 + kh) * 2], fr[s][8 + (j * 2 + kh) * 2 + 1],\
                        acc[i][j], 0, 0, 0);                                     \
            _Pragma("unroll")                                                    \
            for (int i = 0; i < 2; ++i)                                          \
                _Pragma("unroll")                                                \
                for (int j = 0; j < 2; ++j)                                      \
                    acc[i][j] = __builtin_amdgcn_mfma_f32_32x32x16_bf16(         \
                        fr[s][(i * 2 + kh) * 2 + 1], fr[s][8 + (j * 2 + kh) * 2],\
                        acc[i][j], 0, 0, 0);                                     \
        }                                                                        \
    }

#define KSTEP(SC, SN, KB)                                                        \
    {                                                                            \
        if ((KB) < 63) asm volatile("s_waitcnt vmcnt(6)" ::: "memory");          \
        else           asm volatile("s_waitcnt vmcnt(0)" ::: "memory");          \
        asm volatile("s_waitcnt lgkmcnt(0)" ::: "memory");                       \
        __builtin_amdgcn_sched_barrier(0);                                       \
        __builtin_amdgcn_s_barrier();                                            \
        if ((KB) <= 61) STAGE(((KB) + 2) % 3, (KB) + 2);                         \
        READF(SN, sm + ((KB) % 3) * BUFSH);                                      \
        MFMAF(SC);                                                               \
    }

    // prologue: stage tiles 0,1,2; wait tile0 (18 outstanding -> 12); frags(0)
    STAGE(0, 0);
    STAGE(1, 1);
    STAGE(2, 2);
    asm volatile("s_waitcnt vmcnt(12)" ::: "memory");
    __builtin_amdgcn_s_barrier();
    const int fo = ((lane & 31) + 32 * (lane >> 5)) * 8;
    READF(0, sm);

    for (int kb = 1; kb < 63; kb += 2) {
        KSTEP(0, 1, kb);       // MFMA tile kb-1 (set0), read tile kb (set1)
        KSTEP(1, 0, kb + 1);   // MFMA tile kb   (set1), read tile kb+1 (set0)
    }
    // KB=63: MFMA tile 62 (set0), read tile 63 (set1)
    KSTEP(0, 1, 63);
    // epilogue: MFMA tile 63
    asm volatile("s_waitcnt lgkmcnt(0)" ::: "memory");
    __builtin_amdgcn_sched_barrier(0);
    MFMAF(1);
    __syncthreads();   // all waves done with LDS before scan epilogue reuses it

    // ---- fused leaky scan over t (reuse LDS as [64][256] f32 buffer, 64 KB) ----
    float* sb = (float*)sm;
    const float bclamp = fminf(fmaxf(beta1[0], 0.f), 1.f);
    const float th = thr1[0];
    const int sbg = tid >> 8;          // 0..1 ((b,g) group within band)
    const int scol = tid & 255;        // 0..255
    const float bv = bias[bx * 256 + scol];

#pragma unroll
    for (int band = 0; band < 2; ++band) {
        if (wr == band) {
#pragma unroll
            for (int i = 0; i < 2; ++i)
#pragma unroll
                for (int j = 0; j < 2; ++j)
#pragma unroll
                    for (int r = 0; r < 16; ++r) {
                        int lr = i * 32 + (r & 3) + 8 * (r >> 2) + 4 * (lane >> 5);
                        int lc = wc * 64 + j * 32 + (lane & 31);
                        sb[lr * 256 + lc] = acc[i][j][r];
                    }
        }
        __syncthreads();
        float mem = 0.f, cnt = 0.f;
#pragma unroll
        for (int t = 0; t < TSTEPS; ++t) {
            float u = sb[(sbg * 32 + t) * 256 + scol] + bv;
            mem = bclamp * mem + u;
            float spk = mem > th ? 1.f : 0.f;
            mem -= spk * th;
            cnt += spk;
        }
        int bgg = by * 4 + band * 2 + sbg;
        S[(size_t)bgg * GN + bx * 256 + scol] = cnt;
        __syncthreads();
    }
}

// ---------------- FC2 ----------------
__global__ __launch_bounds__(256) void fc2_kernel(
    const float* __restrict__ s, const float* __restrict__ w2,
    const float* __restrict__ b2, float* __restrict__ h2)
{
    int bg  = blockIdx.x;     // 0..255
    int tid = threadIdx.x;
    const float* sp = s + (size_t)bg * HID;
    float part[NCLS];
#pragma unroll
    for (int c = 0; c < NCLS; ++c) part[c] = 0.f;
    for (int d = tid; d < HID; d += 256) {
        float sv = sp[d];
#pragma unroll
        for (int c = 0; c < NCLS; ++c) part[c] += sv * w2[c * HID + d];
    }
#pragma unroll
    for (int c = 0; c < NCLS; ++c)
        for (int off = 32; off > 0; off >>= 1)
            part[c] += __shfl_down(part[c], off, 64);
    __shared__ float red[NCLS][4];
    int wave = tid >> 6, lanei = tid & 63;
    if (lanei == 0)
#pragma unroll
        for (int c = 0; c < NCLS; ++c) red[c][wave] = part[c];
    __syncthreads();
    if (tid < NCLS) {
        float v = red[tid][0] + red[tid][1] + red[tid][2] + red[tid][3] + b2[tid];
        h2[bg * NCLS + tid] = v;
    }
}

// ---------------- scan over G + softmax ----------------
__global__ __launch_bounds__(128) void scan2_kernel(
    const float* __restrict__ h2, const float* __restrict__ beta2,
    const float* __restrict__ thr2, float* __restrict__ out)
{
    __shared__ float logits[BATCH][NCLS];
    int t = threadIdx.x;
    if (t < BATCH * NCLS) {
        int b = t / NCLS, c = t % NCLS;
        float bb = fminf(fmaxf(beta2[0], 0.f), 1.f);
        float th = thr2[0];
        float mem = 0.f, lg = 0.f;
        for (int g = 0; g < GGRP; ++g) {
            float u = h2[(b * GGRP + g) * NCLS + c];
            mem = bb * mem + u;
            float spk = mem > th ? 1.f : 0.f;
            mem -= spk * th;
            lg += spk;
        }
        logits[b][c] = lg;
    }
    __syncthreads();
    if (t < BATCH) {
        float mx = -1e30f;
        for (int c = 0; c < NCLS; ++c) mx = fmaxf(mx, logits[t][c]);
        float e[NCLS];
        float sum = 0.f;
        for (int c = 0; c < NCLS; ++c) { e[c] = expf(logits[t][c] - mx); sum += e[c]; }
        for (int c = 0; c < NCLS; ++c) out[t * NCLS + c] = e[c] / sum;
    }
}

extern "C" void kernel_launch(void* const* d_in, const int* in_sizes, int n_in,
                              void* d_out, int out_size, void* d_ws, size_t ws_size,
                              hipStream_t stream)
{
    const float* x     = (const float*)d_in[0];
    const float* cw    = (const float*)d_in[1];
    const float* cb    = (const float*)d_in[2];
    const float* w1    = (const float*)d_in[3];
    const float* b1    = (const float*)d_in[4];
    const float* beta1 = (const float*)d_in[5];
    const float* thr1  = (const float*)d_in[6];
    const float* w2    = (const float*)d_in[7];
    const float* b2    = (const float*)d_in[8];
    const float* beta2 = (const float*)d_in[9];
    const float* thr2  = (const float*)d_in[10];
    float* out = (float*)d_out;

    // ws: Ahi 32MB | Alo 32MB | Bhi 4MB | Blo 4MB | s 1MB | h2 10KB (~73MB)
    unsigned short* ahi = (unsigned short*)d_ws;
    unsigned short* alo = ahi + (size_t)MROWS * GK;
    unsigned short* bhi = alo + (size_t)MROWS * GK;
    unsigned short* blo = bhi + (size_t)GN * GK;
    float* s  = (float*)(blo + (size_t)GN * GK);
    float* h2 = s + (size_t)BATCH * GGRP * HID;

    conv_pack_kernel<<<4096, 256, 0, stream>>>((const float4*)x, cw, cb, ahi, alo);
    wpack_kernel    <<<256, 256, 0, stream>>>(w1, bhi, blo);
    gemm_scan_kernel<<<256, 512, 0, stream>>>(ahi, alo, bhi, blo, b1, beta1, thr1, s);
    fc2_kernel      <<<256, 256, 0, stream>>>(s, w2, b2, h2);
    scan2_kernel    <<<1, 128, 0, stream>>>(h2, beta2, thr2, out);
}